// Round 1
// baseline (1073.693 us; speedup 1.0000x reference)
//
#include <hip/hip_runtime.h>

#define DD 64

__device__ __forceinline__ float lane_bcast(float v, int lane) {
    return __int_as_float(__builtin_amdgcn_readlane(__float_as_int(v), lane));
}

__global__ __launch_bounds__(256) void zero_kernel(float4* __restrict__ out, int n4) {
    int i = blockIdx.x * blockDim.x + threadIdx.x;
    int stride = gridDim.x * blockDim.x;
    for (; i < n4; i += stride) out[i] = float4{0.f, 0.f, 0.f, 0.f};
}

// One wave per triangle (grid-stride). lane = output column k.
// m[k] = relu( sum_d (x[ab][d]*x[bc][d]) * Wmsg[d][k] );  atomicAdd to agg[ac][k].
// x recomputed on the fly: x[e][k] = feat[e][k] + emb[rel[e]][k].
__global__ __launch_bounds__(256) void tri_kernel(
    const float* __restrict__ feat, const float* __restrict__ emb,
    const float* __restrict__ Wmsg, const int* __restrict__ rel,
    const int* __restrict__ ab, const int* __restrict__ bc,
    const int* __restrict__ ac, float* __restrict__ agg, int T_) {
    const int lane = threadIdx.x & 63;

    // Preload Wmsg column `lane` into registers (coalesced: lanes read consecutive floats).
    float w[DD];
#pragma unroll
    for (int d = 0; d < DD; ++d) w[d] = Wmsg[d * DD + lane];

    const int wave   = (blockIdx.x * blockDim.x + threadIdx.x) >> 6;
    const int nwaves = (gridDim.x * blockDim.x) >> 6;

    for (int t = wave; t < T_; t += nwaves) {
        const int ea = ab[t], eb = bc[t], ec = ac[t];
        const int ra = rel[ea], rb = rel[eb];
        const float xa = feat[ea * DD + lane] + emb[ra * DD + lane];
        const float xb = feat[eb * DD + lane] + emb[rb * DD + lane];
        const float p  = xa * xb;

        // m_lane = sum_d p_d * w[d]; p_d via readlane broadcast. 4 accumulators for ILP.
        float m0 = 0.f, m1 = 0.f, m2 = 0.f, m3 = 0.f;
#pragma unroll
        for (int d = 0; d < DD; d += 4) {
            m0 = fmaf(lane_bcast(p, d + 0), w[d + 0], m0);
            m1 = fmaf(lane_bcast(p, d + 1), w[d + 1], m1);
            m2 = fmaf(lane_bcast(p, d + 2), w[d + 2], m2);
            m3 = fmaf(lane_bcast(p, d + 3), w[d + 3], m3);
        }
        float m = fmaxf((m0 + m1) + (m2 + m3), 0.f);
        atomicAdd(&agg[ec * DD + lane], m);
    }
}

// One wave per edge. out[e][k] = relu( x[e][k] + sum_d agg[e][d] * Wupd[d][k] ).
// agg and out alias (d_out): each wave reads its own row fully before writing it.
__global__ __launch_bounds__(256) void upd_kernel(
    const float* __restrict__ feat, const float* __restrict__ emb,
    const float* __restrict__ Wupd, const int* __restrict__ rel,
    float* __restrict__ agg_out, int E_) {
    const int lane = threadIdx.x & 63;

    float w[DD];
#pragma unroll
    for (int d = 0; d < DD; ++d) w[d] = Wupd[d * DD + lane];

    const int wave   = (blockIdx.x * blockDim.x + threadIdx.x) >> 6;
    const int nwaves = (gridDim.x * blockDim.x) >> 6;

    for (int e = wave; e < E_; e += nwaves) {
        const float a = agg_out[e * DD + lane];
        float u0 = 0.f, u1 = 0.f, u2 = 0.f, u3 = 0.f;
#pragma unroll
        for (int d = 0; d < DD; d += 4) {
            u0 = fmaf(lane_bcast(a, d + 0), w[d + 0], u0);
            u1 = fmaf(lane_bcast(a, d + 1), w[d + 1], u1);
            u2 = fmaf(lane_bcast(a, d + 2), w[d + 2], u2);
            u3 = fmaf(lane_bcast(a, d + 3), w[d + 3], u3);
        }
        const int r = rel[e];
        const float x = feat[e * DD + lane] + emb[r * DD + lane];
        agg_out[e * DD + lane] = fmaxf(x + ((u0 + u1) + (u2 + u3)), 0.f);
    }
}

extern "C" void kernel_launch(void* const* d_in, const int* in_sizes, int n_in,
                              void* d_out, int out_size, void* d_ws, size_t ws_size,
                              hipStream_t stream) {
    const float* feat = (const float*)d_in[0];
    const float* emb  = (const float*)d_in[1];
    const float* Wmsg = (const float*)d_in[2];
    const float* Wupd = (const float*)d_in[3];
    const int*   rel  = (const int*)d_in[4];
    const int*   ab   = (const int*)d_in[5];
    const int*   bc   = (const int*)d_in[6];
    const int*   ac   = (const int*)d_in[7];

    const int E_ = in_sizes[0] / DD;
    const int T_ = in_sizes[5];

    float* agg = (float*)d_out;  // accumulate segment_sum directly into the output buffer

    hipLaunchKernelGGL(zero_kernel, dim3(2048), dim3(256), 0, stream,
                       (float4*)d_out, E_ * (DD / 4));
    hipLaunchKernelGGL(tri_kernel, dim3(4096), dim3(256), 0, stream,
                       feat, emb, Wmsg, rel, ab, bc, ac, agg, T_);
    hipLaunchKernelGGL(upd_kernel, dim3(2048), dim3(256), 0, stream,
                       feat, emb, Wupd, rel, agg, E_);
}

// Round 2
// 1025.047 us; speedup vs baseline: 1.0475x; 1.0475x over previous
//
#include <hip/hip_runtime.h>
#include <hip/hip_bf16.h>

#define DD 64

typedef __attribute__((ext_vector_type(8))) short bf16x8;   // 8 bf16 in 4 VGPRs
typedef __attribute__((ext_vector_type(4))) float f32x4;    // MFMA C/D

__device__ __forceinline__ unsigned short f2bf(float f) {
    // round-to-nearest-even fp32 -> bf16
    unsigned int u = __float_as_uint(f);
    unsigned int r = (u + 0x7fffu + ((u >> 16) & 1u)) >> 16;
    return (unsigned short)r;
}

// Load W (fp32 row-major [64][64]) into per-lane MFMA B-fragments.
// B layout for 16x16x32: lane l holds B[k = ks*32 + (l>>4)*8 + b][col = nt*16 + (l&15)], b=0..7
__device__ __forceinline__ void load_w_frags(const float* __restrict__ W, int lane,
                                             bf16x8 bw[4][2]) {
    const int kl = (lane >> 4) * 8;
    const int cl = lane & 15;
#pragma unroll
    for (int nt = 0; nt < 4; ++nt)
#pragma unroll
        for (int ks = 0; ks < 2; ++ks)
#pragma unroll
            for (int b = 0; b < 8; ++b)
                bw[nt][ks][b] = (short)f2bf(W[(ks * 32 + kl + b) * DD + nt * 16 + cl]);
}

// One wave handles 16 triangles/iteration:
//   phase1: p = (feat[ab]+emb)*(feat[bc]+emb) in lane=d layout -> bf16 -> swizzled LDS
//   phase2: 2x ds_read_b128 A-frag + 8x mfma_f32_16x16x32_bf16 vs W_msg
//   epilogue: relu + coalesced fp32 atomicAdd scatter onto agg[ac]
__global__ __launch_bounds__(256) void tri_kernel(
    const float* __restrict__ feat, const float* __restrict__ emb,
    const float* __restrict__ Wmsg, const int* __restrict__ rel,
    const int* __restrict__ ab, const int* __restrict__ bc,
    const int* __restrict__ ac, float* __restrict__ agg, int T_) {
    __shared__ unsigned short P[4][16 * 64];   // per-wave 2KB bf16 tile, XOR-swizzled

    const int lane = threadIdx.x & 63;
    const int w    = threadIdx.x >> 6;

    bf16x8 bw[4][2];
    load_w_frags(Wmsg, lane, bw);

    const int wave   = (blockIdx.x * blockDim.x + threadIdx.x) >> 6;
    const int nwaves = (gridDim.x * blockDim.x) >> 6;
    const int groups = (T_ + 15) >> 4;

    for (int g = wave; g < groups; g += nwaves) {
        const int bu = __builtin_amdgcn_readfirstlane(g << 4);

        // ---- phase 1: products -> LDS (bf16, swizzled) ----
#pragma unroll 4
        for (int tt = 0; tt < 16; ++tt) {
            const int t = bu + tt;
            float p = 0.f;
            if (t < T_) {
                const int ea = ab[t], eb = bc[t];
                const int ra = rel[ea], rb = rel[eb];
                const float xa = feat[ea * DD + lane] + emb[ra * DD + lane];
                const float xb = feat[eb * DD + lane] + emb[rb * DD + lane];
                p = xa * xb;
            }
            P[w][tt * 64 + (lane ^ ((tt & 7) << 3))] = f2bf(p);
        }

        // ---- phase 2: MFMA ----
        const int row = lane & 15;
        const int d0  = (lane >> 4) * 8;
        const int sw  = (row & 7) << 3;
        const bf16x8 a0 = *reinterpret_cast<const bf16x8*>(&P[w][row * 64 + ((d0)      ^ sw)]);
        const bf16x8 a1 = *reinterpret_cast<const bf16x8*>(&P[w][row * 64 + ((d0 + 32) ^ sw)]);

        f32x4 acc0 = {0.f, 0.f, 0.f, 0.f}, acc1 = acc0, acc2 = acc0, acc3 = acc0;
        acc0 = __builtin_amdgcn_mfma_f32_16x16x32_bf16(a0, bw[0][0], acc0, 0, 0, 0);
        acc0 = __builtin_amdgcn_mfma_f32_16x16x32_bf16(a1, bw[0][1], acc0, 0, 0, 0);
        acc1 = __builtin_amdgcn_mfma_f32_16x16x32_bf16(a0, bw[1][0], acc1, 0, 0, 0);
        acc1 = __builtin_amdgcn_mfma_f32_16x16x32_bf16(a1, bw[1][1], acc1, 0, 0, 0);
        acc2 = __builtin_amdgcn_mfma_f32_16x16x32_bf16(a0, bw[2][0], acc2, 0, 0, 0);
        acc2 = __builtin_amdgcn_mfma_f32_16x16x32_bf16(a1, bw[2][1], acc2, 0, 0, 0);
        acc3 = __builtin_amdgcn_mfma_f32_16x16x32_bf16(a0, bw[3][0], acc3, 0, 0, 0);
        acc3 = __builtin_amdgcn_mfma_f32_16x16x32_bf16(a1, bw[3][1], acc3, 0, 0, 0);

        // ---- epilogue: relu + scatter atomics. C layout: row=(l>>4)*4+r, col=l&15 ----
        const int rb4 = (lane >> 4) * 4;
        const int cl  = lane & 15;
#pragma unroll
        for (int r = 0; r < 4; ++r) {
            const int t = bu + rb4 + r;
            if (t < T_) {
                float* dst = &agg[(long)ac[t] * DD + cl];
                atomicAdd(dst + 0,  fmaxf(acc0[r], 0.f));
                atomicAdd(dst + 16, fmaxf(acc1[r], 0.f));
                atomicAdd(dst + 32, fmaxf(acc2[r], 0.f));
                atomicAdd(dst + 48, fmaxf(acc3[r], 0.f));
            }
        }
    }
}

// One wave handles 16 edges/iteration:
//   phase1: agg row (fp32, coalesced) -> bf16 -> swizzled LDS
//   phase2: 8x MFMA vs W_upd; write u back to LDS (transpose back)
//   phase3: out = relu(feat+emb + u), coalesced row writes (in-place on agg/d_out)
__global__ __launch_bounds__(256) void upd_kernel(
    const float* __restrict__ feat, const float* __restrict__ emb,
    const float* __restrict__ Wupd, const int* __restrict__ rel,
    float* __restrict__ agg_out, int E_) {
    __shared__ unsigned short P[4][16 * 64];
    __shared__ float U[4][16 * 65];            // +1 pad to dodge bank conflicts

    const int lane = threadIdx.x & 63;
    const int w    = threadIdx.x >> 6;

    bf16x8 bw[4][2];
    load_w_frags(Wupd, lane, bw);

    const int wave   = (blockIdx.x * blockDim.x + threadIdx.x) >> 6;
    const int nwaves = (gridDim.x * blockDim.x) >> 6;
    const int groups = (E_ + 15) >> 4;

    for (int g = wave; g < groups; g += nwaves) {
        const int bu = __builtin_amdgcn_readfirstlane(g << 4);

        // ---- phase 1 ----
#pragma unroll 4
        for (int tt = 0; tt < 16; ++tt) {
            const int e = bu + tt;
            const float v = (e < E_) ? agg_out[(long)e * DD + lane] : 0.f;
            P[w][tt * 64 + (lane ^ ((tt & 7) << 3))] = f2bf(v);
        }

        // ---- phase 2 ----
        const int row = lane & 15;
        const int d0  = (lane >> 4) * 8;
        const int sw  = (row & 7) << 3;
        const bf16x8 a0 = *reinterpret_cast<const bf16x8*>(&P[w][row * 64 + ((d0)      ^ sw)]);
        const bf16x8 a1 = *reinterpret_cast<const bf16x8*>(&P[w][row * 64 + ((d0 + 32) ^ sw)]);

        f32x4 acc0 = {0.f, 0.f, 0.f, 0.f}, acc1 = acc0, acc2 = acc0, acc3 = acc0;
        acc0 = __builtin_amdgcn_mfma_f32_16x16x32_bf16(a0, bw[0][0], acc0, 0, 0, 0);
        acc0 = __builtin_amdgcn_mfma_f32_16x16x32_bf16(a1, bw[0][1], acc0, 0, 0, 0);
        acc1 = __builtin_amdgcn_mfma_f32_16x16x32_bf16(a0, bw[1][0], acc1, 0, 0, 0);
        acc1 = __builtin_amdgcn_mfma_f32_16x16x32_bf16(a1, bw[1][1], acc1, 0, 0, 0);
        acc2 = __builtin_amdgcn_mfma_f32_16x16x32_bf16(a0, bw[2][0], acc2, 0, 0, 0);
        acc2 = __builtin_amdgcn_mfma_f32_16x16x32_bf16(a1, bw[2][1], acc2, 0, 0, 0);
        acc3 = __builtin_amdgcn_mfma_f32_16x16x32_bf16(a0, bw[3][0], acc3, 0, 0, 0);
        acc3 = __builtin_amdgcn_mfma_f32_16x16x32_bf16(a1, bw[3][1], acc3, 0, 0, 0);

        const int rb4 = (lane >> 4) * 4;
        const int cl  = lane & 15;
#pragma unroll
        for (int r = 0; r < 4; ++r) {
            U[w][(rb4 + r) * 65 + cl + 0]  = acc0[r];
            U[w][(rb4 + r) * 65 + cl + 16] = acc1[r];
            U[w][(rb4 + r) * 65 + cl + 32] = acc2[r];
            U[w][(rb4 + r) * 65 + cl + 48] = acc3[r];
        }

        // ---- phase 3: fuse x + u, relu, coalesced store ----
#pragma unroll 4
        for (int tt = 0; tt < 16; ++tt) {
            const int e = bu + tt;
            if (e < E_) {
                const int re = rel[e];
                const float x = feat[(long)e * DD + lane] + emb[re * DD + lane];
                agg_out[(long)e * DD + lane] = fmaxf(x + U[w][tt * 65 + lane], 0.f);
            }
        }
    }
}

extern "C" void kernel_launch(void* const* d_in, const int* in_sizes, int n_in,
                              void* d_out, int out_size, void* d_ws, size_t ws_size,
                              hipStream_t stream) {
    const float* feat = (const float*)d_in[0];
    const float* emb  = (const float*)d_in[1];
    const float* Wmsg = (const float*)d_in[2];
    const float* Wupd = (const float*)d_in[3];
    const int*   rel  = (const int*)d_in[4];
    const int*   ab   = (const int*)d_in[5];
    const int*   bc   = (const int*)d_in[6];
    const int*   ac   = (const int*)d_in[7];

    const int E_ = in_sizes[0] / DD;
    const int T_ = in_sizes[5];

    float* agg = (float*)d_out;   // segment_sum accumulates directly into d_out

    hipMemsetAsync(d_out, 0, (size_t)E_ * DD * sizeof(float), stream);
    hipLaunchKernelGGL(tri_kernel, dim3(2048), dim3(256), 0, stream,
                       feat, emb, Wmsg, rel, ab, bc, ac, agg, T_);
    hipLaunchKernelGGL(upd_kernel, dim3(2048), dim3(256), 0, stream,
                       feat, emb, Wupd, rel, agg, E_);
}

// Round 3
// 601.867 us; speedup vs baseline: 1.7839x; 1.7031x over previous
//
#include <hip/hip_runtime.h>
#include <hip/hip_bf16.h>

#define DD 64

typedef __attribute__((ext_vector_type(8))) short bf16x8;   // 8 bf16 in 4 VGPRs
typedef __attribute__((ext_vector_type(4))) float f32x4;    // MFMA C/D

__device__ __forceinline__ unsigned short f2bf(float f) {
    unsigned int u = __float_as_uint(f);
    unsigned int r = (u + 0x7fffu + ((u >> 16) & 1u)) >> 16;   // RNE
    return (unsigned short)r;
}
__device__ __forceinline__ float bf2f(unsigned short u) {
    return __uint_as_float((unsigned int)u << 16);
}
__device__ __forceinline__ unsigned int pack2(float lo, float hi) {
    return (unsigned int)f2bf(lo) | ((unsigned int)f2bf(hi) << 16);
}
__device__ __forceinline__ void pk_atomic_add_bf16(unsigned short* addr, unsigned int data) {
    asm volatile("global_atomic_pk_add_bf16 %0, %1, off" :: "v"(addr), "v"(data) : "memory");
}

// B layout for 16x16x32: lane l holds B[k = ks*32 + (l>>4)*8 + b][col = nt*16 + (l&15)]
__device__ __forceinline__ void load_w_frags(const float* __restrict__ W, int lane,
                                             bf16x8 bw[4][2]) {
    const int kl = (lane >> 4) * 8;
    const int cl = lane & 15;
#pragma unroll
    for (int nt = 0; nt < 4; ++nt)
#pragma unroll
        for (int ks = 0; ks < 2; ++ks)
#pragma unroll
            for (int b = 0; b < 8; ++b)
                bw[nt][ks][b] = (short)f2bf(W[(ks * 32 + kl + b) * DD + nt * 16 + cl]);
}

#define MFMA8(A0, A1)                                                          \
    acc0 = __builtin_amdgcn_mfma_f32_16x16x32_bf16(A0, bw[0][0], acc0, 0, 0, 0); \
    acc0 = __builtin_amdgcn_mfma_f32_16x16x32_bf16(A1, bw[0][1], acc0, 0, 0, 0); \
    acc1 = __builtin_amdgcn_mfma_f32_16x16x32_bf16(A0, bw[1][0], acc1, 0, 0, 0); \
    acc1 = __builtin_amdgcn_mfma_f32_16x16x32_bf16(A1, bw[1][1], acc1, 0, 0, 0); \
    acc2 = __builtin_amdgcn_mfma_f32_16x16x32_bf16(A0, bw[2][0], acc2, 0, 0, 0); \
    acc2 = __builtin_amdgcn_mfma_f32_16x16x32_bf16(A1, bw[2][1], acc2, 0, 0, 0); \
    acc3 = __builtin_amdgcn_mfma_f32_16x16x32_bf16(A0, bw[3][0], acc3, 0, 0, 0); \
    acc3 = __builtin_amdgcn_mfma_f32_16x16x32_bf16(A1, bw[3][1], acc3, 0, 0, 0);

// ---------- fast path ----------

// x[e][d] = bf16(feat[e][d] + emb[rel[e]][d]); 128 MB table, L3-resident.
__global__ __launch_bounds__(256) void xprep_kernel(
    const float4* __restrict__ feat4, const float4* __restrict__ emb4,
    const int* __restrict__ rel, unsigned short* __restrict__ xtab, int n4) {
    int i = blockIdx.x * blockDim.x + threadIdx.x;
    const int stride = gridDim.x * blockDim.x;
    for (; i < n4; i += stride) {
        const int e  = i >> 4;
        const int re = rel[e];
        const float4 f = feat4[i];
        const float4 g = emb4[re * 16 + (i & 15)];
        ushort4 o;
        o.x = f2bf(f.x + g.x); o.y = f2bf(f.y + g.y);
        o.z = f2bf(f.z + g.z); o.w = f2bf(f.w + g.w);
        *reinterpret_cast<ushort4*>(&xtab[(size_t)i * 4]) = o;
    }
}

// One wave / 16 triangles: lane-parallel index prefetch -> 32 independent row
// gathers from the bf16 x-table -> swizzled LDS -> 8 MFMA -> pk-bf16 atomics.
__global__ __launch_bounds__(256) void tri_fast(
    const unsigned short* __restrict__ xtab, const float* __restrict__ Wmsg,
    const int* __restrict__ ab, const int* __restrict__ bc,
    const int* __restrict__ ac, unsigned short* __restrict__ aggbf, int T_) {
    __shared__ unsigned short P[4][16 * 64];

    const int lane = threadIdx.x & 63;
    const int w    = threadIdx.x >> 6;

    bf16x8 bw[4][2];
    load_w_frags(Wmsg, lane, bw);

    const int wave   = (blockIdx.x * blockDim.x + threadIdx.x) >> 6;
    const int nwaves = (gridDim.x * blockDim.x) >> 6;
    const int groups = T_ >> 4;   // T_ % 16 == 0 guaranteed by launcher

    for (int g = wave; g < groups; g += nwaves) {
        const int bu  = g << 4;
        const int t16 = bu + (lane & 15);
        const int ia  = ab[t16];
        const int ib  = bc[t16];
        const int ic  = ac[t16];

        // ---- phase 1: all 32 gathers independent (indices via readlane) ----
#pragma unroll
        for (int tt = 0; tt < 16; ++tt) {
            const int ea = __builtin_amdgcn_readlane(ia, tt);
            const int eb = __builtin_amdgcn_readlane(ib, tt);
            const float xa = bf2f(xtab[(size_t)ea * DD + lane]);
            const float xb = bf2f(xtab[(size_t)eb * DD + lane]);
            P[w][tt * 64 + (lane ^ ((tt & 7) << 3))] = f2bf(xa * xb);
        }

        // ---- phase 2: MFMA ----
        const int row = lane & 15;
        const int d0  = (lane >> 4) * 8;
        const int sw  = (row & 7) << 3;
        const bf16x8 a0 = *reinterpret_cast<const bf16x8*>(&P[w][row * 64 + ((d0)      ^ sw)]);
        const bf16x8 a1 = *reinterpret_cast<const bf16x8*>(&P[w][row * 64 + ((d0 + 32) ^ sw)]);

        f32x4 acc0 = {0.f, 0.f, 0.f, 0.f}, acc1 = acc0, acc2 = acc0, acc3 = acc0;
        MFMA8(a0, a1)

        // ---- epilogue: relu + packed bf16 atomics (all 64 lanes active) ----
        const int rb4 = (lane >> 4) * 4;
        const int cl  = lane & 15;
        const int odd = lane & 1;
#pragma unroll
        for (int r = 0; r < 4; ++r) {
            const int ec = __shfl(ic, rb4 + r, 64);
            const float o0 = fmaxf(acc0[r], 0.f), o1 = fmaxf(acc1[r], 0.f);
            const float o2 = fmaxf(acc2[r], 0.f), o3 = fmaxf(acc3[r], 0.f);
            const float n0 = __shfl_xor(o0, 1, 64), n1 = __shfl_xor(o1, 1, 64);
            const float n2 = __shfl_xor(o2, 1, 64), n3 = __shfl_xor(o3, 1, 64);
            // even lanes cover cols (cl,cl+1)+{0,16}; odd lanes cols (cl-1,cl)+{32,48}
            const int base      = odd ? (cl - 1 + 32) : cl;
            const unsigned dA   = odd ? pack2(n2, o2) : pack2(o0, n0);
            const unsigned dB   = odd ? pack2(n3, o3) : pack2(o1, n1);
            unsigned short* dst = &aggbf[(size_t)ec * DD + base];
            pk_atomic_add_bf16(dst + 0,  dA);
            pk_atomic_add_bf16(dst + 16, dB);
        }
    }
}

// One wave / 16 edges: agg(bf16) -> LDS -> MFMA vs W_upd -> relu(x + u) -> fp32 out.
__global__ __launch_bounds__(256) void upd_fast(
    const unsigned short* __restrict__ xtab, const unsigned short* __restrict__ aggbf,
    const float* __restrict__ Wupd, float* __restrict__ out, int E_) {
    __shared__ unsigned short P[4][16 * 64];
    __shared__ float U[4][16 * 65];

    const int lane = threadIdx.x & 63;
    const int w    = threadIdx.x >> 6;

    bf16x8 bw[4][2];
    load_w_frags(Wupd, lane, bw);

    const int wave   = (blockIdx.x * blockDim.x + threadIdx.x) >> 6;
    const int nwaves = (gridDim.x * blockDim.x) >> 6;
    const int groups = E_ >> 4;   // E_ % 16 == 0 guaranteed by launcher

    for (int g = wave; g < groups; g += nwaves) {
        const int bu = g << 4;

#pragma unroll
        for (int tt = 0; tt < 16; ++tt)
            P[w][tt * 64 + (lane ^ ((tt & 7) << 3))] = aggbf[(size_t)(bu + tt) * DD + lane];

        const int row = lane & 15;
        const int d0  = (lane >> 4) * 8;
        const int sw  = (row & 7) << 3;
        const bf16x8 a0 = *reinterpret_cast<const bf16x8*>(&P[w][row * 64 + ((d0)      ^ sw)]);
        const bf16x8 a1 = *reinterpret_cast<const bf16x8*>(&P[w][row * 64 + ((d0 + 32) ^ sw)]);

        f32x4 acc0 = {0.f, 0.f, 0.f, 0.f}, acc1 = acc0, acc2 = acc0, acc3 = acc0;
        MFMA8(a0, a1)

        const int rb4 = (lane >> 4) * 4;
        const int cl  = lane & 15;
#pragma unroll
        for (int r = 0; r < 4; ++r) {
            U[w][(rb4 + r) * 65 + cl + 0]  = acc0[r];
            U[w][(rb4 + r) * 65 + cl + 16] = acc1[r];
            U[w][(rb4 + r) * 65 + cl + 32] = acc2[r];
            U[w][(rb4 + r) * 65 + cl + 48] = acc3[r];
        }

#pragma unroll
        for (int tt = 0; tt < 16; ++tt) {
            const int e   = bu + tt;
            const float x = bf2f(xtab[(size_t)e * DD + lane]);
            out[(size_t)e * DD + lane] = fmaxf(x + U[w][tt * 65 + lane], 0.f);
        }
    }
}

// ---------- fallback path (round-2 kernels, fp32 atomics into d_out) ----------

__global__ __launch_bounds__(256) void tri_fb(
    const float* __restrict__ feat, const float* __restrict__ emb,
    const float* __restrict__ Wmsg, const int* __restrict__ rel,
    const int* __restrict__ ab, const int* __restrict__ bc,
    const int* __restrict__ ac, float* __restrict__ agg, int T_) {
    __shared__ unsigned short P[4][16 * 64];
    const int lane = threadIdx.x & 63;
    const int w    = threadIdx.x >> 6;
    bf16x8 bw[4][2];
    load_w_frags(Wmsg, lane, bw);
    const int wave   = (blockIdx.x * blockDim.x + threadIdx.x) >> 6;
    const int nwaves = (gridDim.x * blockDim.x) >> 6;
    const int groups = (T_ + 15) >> 4;
    for (int g = wave; g < groups; g += nwaves) {
        const int bu = __builtin_amdgcn_readfirstlane(g << 4);
#pragma unroll 4
        for (int tt = 0; tt < 16; ++tt) {
            const int t = bu + tt;
            float p = 0.f;
            if (t < T_) {
                const int ea = ab[t], eb = bc[t];
                const float xa = feat[ea * DD + lane] + emb[rel[ea] * DD + lane];
                const float xb = feat[eb * DD + lane] + emb[rel[eb] * DD + lane];
                p = xa * xb;
            }
            P[w][tt * 64 + (lane ^ ((tt & 7) << 3))] = f2bf(p);
        }
        const int row = lane & 15;
        const int d0  = (lane >> 4) * 8;
        const int sw  = (row & 7) << 3;
        const bf16x8 a0 = *reinterpret_cast<const bf16x8*>(&P[w][row * 64 + ((d0)      ^ sw)]);
        const bf16x8 a1 = *reinterpret_cast<const bf16x8*>(&P[w][row * 64 + ((d0 + 32) ^ sw)]);
        f32x4 acc0 = {0.f, 0.f, 0.f, 0.f}, acc1 = acc0, acc2 = acc0, acc3 = acc0;
        MFMA8(a0, a1)
        const int rb4 = (lane >> 4) * 4;
        const int cl  = lane & 15;
#pragma unroll
        for (int r = 0; r < 4; ++r) {
            const int t = bu + rb4 + r;
            if (t < T_) {
                float* dst = &agg[(size_t)ac[t] * DD + cl];
                atomicAdd(dst + 0,  fmaxf(acc0[r], 0.f));
                atomicAdd(dst + 16, fmaxf(acc1[r], 0.f));
                atomicAdd(dst + 32, fmaxf(acc2[r], 0.f));
                atomicAdd(dst + 48, fmaxf(acc3[r], 0.f));
            }
        }
    }
}

__global__ __launch_bounds__(256) void upd_fb(
    const float* __restrict__ feat, const float* __restrict__ emb,
    const float* __restrict__ Wupd, const int* __restrict__ rel,
    float* __restrict__ agg_out, int E_) {
    __shared__ unsigned short P[4][16 * 64];
    __shared__ float U[4][16 * 65];
    const int lane = threadIdx.x & 63;
    const int w    = threadIdx.x >> 6;
    bf16x8 bw[4][2];
    load_w_frags(Wupd, lane, bw);
    const int wave   = (blockIdx.x * blockDim.x + threadIdx.x) >> 6;
    const int nwaves = (gridDim.x * blockDim.x) >> 6;
    const int groups = (E_ + 15) >> 4;
    for (int g = wave; g < groups; g += nwaves) {
        const int bu = __builtin_amdgcn_readfirstlane(g << 4);
#pragma unroll 4
        for (int tt = 0; tt < 16; ++tt) {
            const int e = bu + tt;
            const float v = (e < E_) ? agg_out[(size_t)e * DD + lane] : 0.f;
            P[w][tt * 64 + (lane ^ ((tt & 7) << 3))] = f2bf(v);
        }
        const int row = lane & 15;
        const int d0  = (lane >> 4) * 8;
        const int sw  = (row & 7) << 3;
        const bf16x8 a0 = *reinterpret_cast<const bf16x8*>(&P[w][row * 64 + ((d0)      ^ sw)]);
        const bf16x8 a1 = *reinterpret_cast<const bf16x8*>(&P[w][row * 64 + ((d0 + 32) ^ sw)]);
        f32x4 acc0 = {0.f, 0.f, 0.f, 0.f}, acc1 = acc0, acc2 = acc0, acc3 = acc0;
        MFMA8(a0, a1)
        const int rb4 = (lane >> 4) * 4;
        const int cl  = lane & 15;
#pragma unroll
        for (int r = 0; r < 4; ++r) {
            U[w][(rb4 + r) * 65 + cl + 0]  = acc0[r];
            U[w][(rb4 + r) * 65 + cl + 16] = acc1[r];
            U[w][(rb4 + r) * 65 + cl + 32] = acc2[r];
            U[w][(rb4 + r) * 65 + cl + 48] = acc3[r];
        }
#pragma unroll 4
        for (int tt = 0; tt < 16; ++tt) {
            const int e = bu + tt;
            if (e < E_) {
                const float x = feat[(size_t)e * DD + lane] + emb[rel[e] * DD + lane];
                agg_out[(size_t)e * DD + lane] = fmaxf(x + U[w][tt * 65 + lane], 0.f);
            }
        }
    }
}

extern "C" void kernel_launch(void* const* d_in, const int* in_sizes, int n_in,
                              void* d_out, int out_size, void* d_ws, size_t ws_size,
                              hipStream_t stream) {
    const float* feat = (const float*)d_in[0];
    const float* emb  = (const float*)d_in[1];
    const float* Wmsg = (const float*)d_in[2];
    const float* Wupd = (const float*)d_in[3];
    const int*   rel  = (const int*)d_in[4];
    const int*   ab   = (const int*)d_in[5];
    const int*   bc   = (const int*)d_in[6];
    const int*   ac   = (const int*)d_in[7];

    const int E_ = in_sizes[0] / DD;
    const int T_ = in_sizes[5];

    const size_t xbytes = (size_t)E_ * DD * sizeof(unsigned short);
    const bool fast = (ws_size >= 2 * xbytes) && ((T_ & 15) == 0) && ((E_ & 15) == 0);

    if (fast) {
        unsigned short* xtab  = (unsigned short*)d_ws;
        unsigned short* aggbf = (unsigned short*)((char*)d_ws + xbytes);
        hipMemsetAsync(aggbf, 0, xbytes, stream);
        hipLaunchKernelGGL(xprep_kernel, dim3(2048), dim3(256), 0, stream,
                           (const float4*)feat, (const float4*)emb, rel, xtab, E_ * 16);
        hipLaunchKernelGGL(tri_fast, dim3(2048), dim3(256), 0, stream,
                           xtab, Wmsg, ab, bc, ac, aggbf, T_);
        hipLaunchKernelGGL(upd_fast, dim3(2048), dim3(256), 0, stream,
                           xtab, aggbf, Wupd, (float*)d_out, E_);
    } else {
        float* agg = (float*)d_out;
        hipMemsetAsync(d_out, 0, (size_t)E_ * DD * sizeof(float), stream);
        hipLaunchKernelGGL(tri_fb, dim3(2048), dim3(256), 0, stream,
                           feat, emb, Wmsg, rel, ab, bc, ac, agg, T_);
        hipLaunchKernelGGL(upd_fb, dim3(2048), dim3(256), 0, stream,
                           feat, emb, Wupd, rel, agg, E_);
    }
}